// Round 7
// baseline (1520.341 us; speedup 1.0000x reference)
//
#include <hip/hip_runtime.h>
#include <hip/hip_bf16.h>
#include <hip/hip_cooperative_groups.h>

namespace cg = cooperative_groups;

typedef unsigned short u16;
typedef __attribute__((ext_vector_type(8))) short bf16x8;
typedef __attribute__((ext_vector_type(4))) float f32x4;

#define NDIM 128
#define EDIM 32
#define HSTR 136     // gemm h LDS stride (u16): 16B aligned, 2-way banks (free)

__device__ __forceinline__ float bf2f(u16 u) {
    union { unsigned int i; float f; } v; v.i = ((unsigned int)u) << 16; return v.f;
}
__device__ __forceinline__ u16 f2bf(float f) {
    __hip_bfloat16 h = __float2bfloat16(f);
    return *reinterpret_cast<u16*>(&h);
}

// ---------------------------------------------------------------------------
// K1 (cooperative): zero cnt/cur/stats + dtype-detect + hist + scan + scatter
// grid MUST be 256 blocks x 256 threads (all co-resident on 256 CUs).
// ---------------------------------------------------------------------------
__global__ __launch_bounds__(256) void csr_coop_kernel(
    const int* __restrict__ ei, const void* __restrict__ x,
    int* __restrict__ cnt, int* __restrict__ cur, int* __restrict__ row_ptr,
    int* __restrict__ eidx, int* __restrict__ src_s, float* __restrict__ stats,
    int* __restrict__ flag, int* __restrict__ bsum, int N, int E) {
    cg::grid_group grid = cg::this_grid();
    __shared__ int sdata[256];
    __shared__ int sdata2[256];
    __shared__ int dcnt;
    const int t = threadIdx.x;
    const int tid = blockIdx.x * 256 + t;
    const int nthr = gridDim.x * 256;

    // phase 0: zero + dtype detect (fp32's low u16 has uniform-random "exponent")
    for (int i = tid; i < N; i += nthr) { cnt[i] = 0; cur[i] = 0; }
    if (tid < 512) stats[tid] = 0.0f;
    if (blockIdx.x == 0) {
        if (t == 0) dcnt = 0;
        __syncthreads();
        if (t < 64) {
            const u16* p = (const u16*)x;
            int crazy = 0;
            for (int i = t; i < 512; i += 64) {
                u16 v = p[2 * i];
                int e = (v >> 7) & 0xFF;
                if (e != 0 && (e < 100 || e > 150)) crazy++;
            }
            atomicAdd(&dcnt, crazy);
        }
        __syncthreads();
        if (t == 0) *flag = (dcnt > 128) ? 0 : 1;
    }
    grid.sync();

    // phase 1: histogram of dst
    for (int e = tid; e < E; e += nthr) atomicAdd(&cnt[ei[E + e]], 1);
    grid.sync();

    // phase 2: block-local inclusive scan (one element per thread; N <= nthr)
    int v = (tid < N) ? cnt[tid] : 0;
    sdata[t] = v;
    __syncthreads();
    for (int off = 1; off < 256; off <<= 1) {
        int u = (t >= off) ? sdata[t - off] : 0;
        __syncthreads();
        sdata[t] += u;
        __syncthreads();
    }
    if (t == 255) bsum[blockIdx.x] = sdata[255];
    grid.sync();

    // phase 3: block 0 scans the 256 block sums -> exclusive offsets
    if (blockIdx.x == 0) {
        int bv = sdata2[0];  // placeholder init, overwritten below
        bv = bsum[t];
        sdata2[t] = bv;
        __syncthreads();
        for (int off = 1; off < 256; off <<= 1) {
            int u = (t >= off) ? sdata2[t - off] : 0;
            __syncthreads();
            sdata2[t] += u;
            __syncthreads();
        }
        bsum[t] = sdata2[t] - bv;   // exclusive
    }
    grid.sync();

    // phase 4: row_ptr
    if (tid < N) row_ptr[tid] = bsum[blockIdx.x] + sdata[t] - v;
    if (tid == 0) row_ptr[N] = E;
    grid.sync();

    // phase 5: scatter edges into CSR slots
    for (int e = tid; e < E; e += nthr) {
        int dst = ei[E + e];
        int slot = row_ptr[dst] + atomicAdd(&cur[dst], 1);
        eidx[slot] = e;
        src_s[slot] = ei[e];
    }
}

// ---------------------------------------------------------------------------
// K2: pre-transpose weights to bf16 (hi) in workspace.
// WeT[d][k] (d<128,k<32), W1T[c][k], W2T[c][k] (c,k<128).
// ---------------------------------------------------------------------------
__global__ __launch_bounds__(256) void prep_kernel(
    const void* __restrict__ We, const void* __restrict__ W1,
    const void* __restrict__ W2, u16* __restrict__ WeT,
    u16* __restrict__ W1T, u16* __restrict__ W2T, const int* __restrict__ flag) {
    const bool bf = (*flag != 0);
    const int t = threadIdx.x;
    for (int i = t; i < NDIM * EDIM; i += 256) {
        int k = i >> 7, d = i & 127;
        WeT[d * EDIM + k] = bf ? ((const u16*)We)[i] : f2bf(((const float*)We)[i]);
    }
    for (int i = t; i < NDIM * NDIM; i += 256) {
        int k = i >> 7, c = i & 127;
        W1T[c * NDIM + k] = bf ? ((const u16*)W1)[i] : f2bf(((const float*)W1)[i]);
        W2T[c * NDIM + k] = bf ? ((const u16*)W2)[i] : f2bf(((const float*)W2)[i]);
    }
}

// ---------------------------------------------------------------------------
// K3: CSR aggregation with MFMA edge-embed (both dtypes).
// One wave per node. Per 16-edge group:
//   A[m=edge(l16)][k=q*8+j] = attr row (bf16-cvt if fp32)
//   B[k][n=dim(l16)] = WeT, hoisted to VGPRs (8 frags, loop-invariant)
//   D = mfma(A, B, C=bias) -> relu + validity mask -> part[8]
// x stays fp32-exact; quad-parallel gather, LDS exchange per node.
// ---------------------------------------------------------------------------
__global__ __launch_bounds__(256) void agg_kernel(
    const int* __restrict__ row_ptr, const int* __restrict__ eidx,
    const int* __restrict__ src_sorted, const void* __restrict__ edge_attr,
    const void* __restrict__ x, const u16* __restrict__ WeT,
    const void* __restrict__ be, float* __restrict__ agg, int N,
    const int* __restrict__ flag) {
    const bool bf = (*flag != 0);
    __shared__ float xsumQ[4][4][NDIM];

    const int lane = threadIdx.x & 63;
    const int wid = threadIdx.x >> 6;
    const int q = lane >> 4, l16 = lane & 15;

    bf16x8 bfr[8];
#pragma unroll
    for (int nt = 0; nt < 8; ++nt)
        bfr[nt] = *(const bf16x8*)(WeT + (nt * 16 + l16) * EDIM + q * 8);
    f32x4 biasv[8];
#pragma unroll
    for (int nt = 0; nt < 8; ++nt) {
        float bv = bf ? bf2f(((const u16*)be)[nt * 16 + l16])
                      : ((const float*)be)[nt * 16 + l16];
        biasv[nt] = (f32x4){bv, bv, bv, bv};
    }

    const int gwave = blockIdx.x * 4 + wid;
    const int nwaves = gridDim.x * 4;

    for (int n = gwave; n < N; n += nwaves) {
        const int p0 = row_ptr[n], p1 = row_ptr[n + 1];
        float part[8];
#pragma unroll
        for (int nt = 0; nt < 8; ++nt) part[nt] = 0.0f;
        float xa[8];
#pragma unroll
        for (int j = 0; j < 8; ++j) xa[j] = 0.0f;

        for (int base = p0; base < p1; base += 16) {
            const int cnt = min(16, p1 - base);
            // x-gather: quad q handles edges base+q, +4, +8, +12
            if (bf) {
                for (int t = q; t < cnt; t += 4) {
                    int s = src_sorted[base + t];
                    const u16* xr = (const u16*)x + (long)s * NDIM + l16 * 8;
                    ushort4 a = *(const ushort4*)xr;
                    ushort4 b2 = *(const ushort4*)(xr + 4);
                    xa[0] += bf2f(a.x); xa[1] += bf2f(a.y);
                    xa[2] += bf2f(a.z); xa[3] += bf2f(a.w);
                    xa[4] += bf2f(b2.x); xa[5] += bf2f(b2.y);
                    xa[6] += bf2f(b2.z); xa[7] += bf2f(b2.w);
                }
            } else {
                for (int t = q; t < cnt; t += 4) {
                    int s = src_sorted[base + t];
                    const float* xr = (const float*)x + (long)s * NDIM + l16 * 8;
                    float4 a = *(const float4*)xr;
                    float4 b2 = *(const float4*)(xr + 4);
                    xa[0] += a.x; xa[1] += a.y; xa[2] += a.z; xa[3] += a.w;
                    xa[4] += b2.x; xa[5] += b2.y; xa[6] += b2.z; xa[7] += b2.w;
                }
            }
            // A-frag: attr row of edge base+l16
            int eid = eidx[min(base + l16, p1 - 1)];
            bf16x8 af;
            if (bf) {
                af = *(const bf16x8*)((const u16*)edge_attr + (long)eid * EDIM + q * 8);
            } else {
                const float* ar = (const float*)edge_attr + (long)eid * EDIM + q * 8;
                float4 a0 = *(const float4*)ar;
                float4 a1 = *(const float4*)(ar + 4);
                af[0] = (short)f2bf(a0.x); af[1] = (short)f2bf(a0.y);
                af[2] = (short)f2bf(a0.z); af[3] = (short)f2bf(a0.w);
                af[4] = (short)f2bf(a1.x); af[5] = (short)f2bf(a1.y);
                af[6] = (short)f2bf(a1.z); af[7] = (short)f2bf(a1.w);
            }
#pragma unroll
            for (int nt = 0; nt < 8; ++nt) {
                f32x4 c = __builtin_amdgcn_mfma_f32_16x16x32_bf16(af, bfr[nt], biasv[nt], 0, 0, 0);
#pragma unroll
                for (int r = 0; r < 4; ++r)
                    if (q * 4 + r < cnt) part[nt] += fmaxf(c[r], 0.0f);
            }
        }
        // cross-quad reduce of MFMA parts
#pragma unroll
        for (int nt = 0; nt < 8; ++nt) {
            part[nt] += __shfl_xor(part[nt], 16);
            part[nt] += __shfl_xor(part[nt], 32);
        }
        // exchange x partials through LDS (per-wave slice)
        *(float4*)&xsumQ[wid][q][l16 * 8 + 0] = make_float4(xa[0], xa[1], xa[2], xa[3]);
        *(float4*)&xsumQ[wid][q][l16 * 8 + 4] = make_float4(xa[4], xa[5], xa[6], xa[7]);
#pragma unroll
        for (int j = 0; j < 2; ++j) {
            int nt = 2 * q + j;
            int d = nt * 16 + l16;
            float xs = xsumQ[wid][0][d] + xsumQ[wid][1][d] +
                       xsumQ[wid][2][d] + xsumQ[wid][3][d];
            agg[(long)n * NDIM + d] = part[nt] + xs;
        }
    }
}

// ---------------------------------------------------------------------------
// split h -> bf16 hi+lo in LDS (fp32-accurate through 2 MFMAs)
// ---------------------------------------------------------------------------
__device__ __forceinline__ void split_store(u16* hHi, u16* hLo, int r, int c, float4 h) {
    ushort4 hi, lo;
    hi.x = f2bf(h.x); lo.x = f2bf(h.x - bf2f(hi.x));
    hi.y = f2bf(h.y); lo.y = f2bf(h.y - bf2f(hi.y));
    hi.z = f2bf(h.z); lo.z = f2bf(h.z - bf2f(hi.z));
    hi.w = f2bf(h.w); lo.w = f2bf(h.w - bf2f(hi.w));
    *(ushort4*)&hHi[r * HSTR + c] = hi;
    *(ushort4*)&hLo[r * HSTR + c] = lo;
}

// ---------------------------------------------------------------------------
// K4: h0 = (1+eps)*x + agg ; h1 = h0 @ W1 + b1 ; col stats.
// B-frags straight from global W1T (32 KB, L1-resident). 64 rows/block.
// ---------------------------------------------------------------------------
__global__ __launch_bounds__(256) void gemm1_kernel(
    const void* __restrict__ x, const float* __restrict__ agg,
    const void* __restrict__ eps_p, const u16* __restrict__ WT,
    const void* __restrict__ b, float* __restrict__ hout,
    float* __restrict__ stats, int M, const int* __restrict__ flag) {
    const bool bf = (*flag != 0);
    __shared__ u16 hHi[64 * HSTR];
    __shared__ u16 hLo[64 * HSTR];
    __shared__ float redS[4][NDIM];
    __shared__ float redQ[4][NDIM];

    const int tid = threadIdx.x;
    const int row0 = blockIdx.x * 64;
    const float onepeps = 1.0f + (bf ? bf2f(((const u16*)eps_p)[0])
                                     : ((const float*)eps_p)[0]);

#pragma unroll
    for (int i = 0; i < 8; ++i) {
        int idx = (tid + i * 256) * 4;
        int r = idx >> 7, c = idx & 127;
        int row = row0 + r;
        float4 h = make_float4(0.f, 0.f, 0.f, 0.f);
        if (row < M) {
            float4 ag = *(const float4*)(agg + (long)row * NDIM + c);
            float4 xv;
            if (bf) {
                ushort4 u = *(const ushort4*)((const u16*)x + (long)row * NDIM + c);
                xv = make_float4(bf2f(u.x), bf2f(u.y), bf2f(u.z), bf2f(u.w));
            } else {
                xv = *(const float4*)((const float*)x + (long)row * NDIM + c);
            }
            h = make_float4(onepeps * xv.x + ag.x, onepeps * xv.y + ag.y,
                            onepeps * xv.z + ag.z, onepeps * xv.w + ag.w);
        }
        split_store(hHi, hLo, r, c, h);
    }
    __syncthreads();

    const int lane = tid & 63, w = tid >> 6;
    const int q = lane >> 4, l16 = lane & 15;

    f32x4 acc[8];
#pragma unroll
    for (int nt = 0; nt < 8; ++nt) {
        float bj = bf ? bf2f(((const u16*)b)[nt * 16 + l16])
                      : ((const float*)b)[nt * 16 + l16];
        acc[nt] = (f32x4){bj, bj, bj, bj};
    }
#pragma unroll
    for (int ks = 0; ks < 4; ++ks) {
        bf16x8 aHi = *(const bf16x8*)&hHi[(w * 16 + l16) * HSTR + ks * 32 + q * 8];
        bf16x8 aLo = *(const bf16x8*)&hLo[(w * 16 + l16) * HSTR + ks * 32 + q * 8];
#pragma unroll
        for (int nt = 0; nt < 8; ++nt) {
            bf16x8 bfr = *(const bf16x8*)(WT + (long)(nt * 16 + l16) * NDIM + ks * 32 + q * 8);
            acc[nt] = __builtin_amdgcn_mfma_f32_16x16x32_bf16(aHi, bfr, acc[nt], 0, 0, 0);
            acc[nt] = __builtin_amdgcn_mfma_f32_16x16x32_bf16(aLo, bfr, acc[nt], 0, 0, 0);
        }
    }

#pragma unroll
    for (int nt = 0; nt < 8; ++nt) {
        float s = 0.f, qs = 0.f;
#pragma unroll
        for (int r = 0; r < 4; ++r) {
            int row = row0 + w * 16 + q * 4 + r;
            if (row < M) {
                float v = acc[nt][r];
                hout[(long)row * NDIM + nt * 16 + l16] = v;
                s += v; qs += v * v;
            }
        }
        s += __shfl_xor(s, 16);  s += __shfl_xor(s, 32);
        qs += __shfl_xor(qs, 16); qs += __shfl_xor(qs, 32);
        if (nt == 2 * q || nt == 2 * q + 1) {
            redS[w][nt * 16 + l16] = s;
            redQ[w][nt * 16 + l16] = qs;
        }
    }
    __syncthreads();
    if (tid < NDIM) {
        atomicAdd(&stats[tid], redS[0][tid] + redS[1][tid] + redS[2][tid] + redS[3][tid]);
    } else {
        int c = tid - NDIM;
        atomicAdd(&stats[NDIM + c], redQ[0][c] + redQ[1][c] + redQ[2][c] + redQ[3][c]);
    }
}

// ---------------------------------------------------------------------------
// K5: a = relu(BN1(h1)) ; h2 = a @ W2 + b2 ; col stats.
// ---------------------------------------------------------------------------
__global__ __launch_bounds__(256) void gemm2_kernel(
    const float* __restrict__ h1, const float* __restrict__ statsIn,
    const void* __restrict__ g, const void* __restrict__ beta,
    const u16* __restrict__ WT, const void* __restrict__ b,
    float* __restrict__ hout, float* __restrict__ stats, int M,
    const int* __restrict__ flag) {
    const bool bf = (*flag != 0);
    __shared__ u16 hHi[64 * HSTR];
    __shared__ u16 hLo[64 * HSTR];
    __shared__ float redS[4][NDIM];
    __shared__ float redQ[4][NDIM];
    __shared__ float scaleL[NDIM];
    __shared__ float shiftL[NDIM];

    const int tid = threadIdx.x;
    const int row0 = blockIdx.x * 64;

    if (tid < NDIM) {
        float s = statsIn[tid], qv = statsIn[NDIM + tid];
        float invM = 1.0f / (float)M;
        float mean = s * invM;
        float var = fmaxf(qv * invM - mean * mean, 0.0f) + 1e-5f;
        float gv = bf ? bf2f(((const u16*)g)[tid]) : ((const float*)g)[tid];
        float bv = bf ? bf2f(((const u16*)beta)[tid]) : ((const float*)beta)[tid];
        float sc = gv * rsqrtf(var);
        scaleL[tid] = sc;
        shiftL[tid] = bv - mean * sc;
    }
    __syncthreads();

#pragma unroll
    for (int i = 0; i < 8; ++i) {
        int idx = (tid + i * 256) * 4;
        int r = idx >> 7, c = idx & 127;
        int row = row0 + r;
        float4 h = make_float4(0.f, 0.f, 0.f, 0.f);
        if (row < M) {
            float4 hv = *(const float4*)(h1 + (long)row * NDIM + c);
            h.x = fmaxf(hv.x * scaleL[c + 0] + shiftL[c + 0], 0.0f);
            h.y = fmaxf(hv.y * scaleL[c + 1] + shiftL[c + 1], 0.0f);
            h.z = fmaxf(hv.z * scaleL[c + 2] + shiftL[c + 2], 0.0f);
            h.w = fmaxf(hv.w * scaleL[c + 3] + shiftL[c + 3], 0.0f);
        }
        split_store(hHi, hLo, r, c, h);
    }
    __syncthreads();

    const int lane = tid & 63, w = tid >> 6;
    const int q = lane >> 4, l16 = lane & 15;

    f32x4 acc[8];
#pragma unroll
    for (int nt = 0; nt < 8; ++nt) {
        float bj = bf ? bf2f(((const u16*)b)[nt * 16 + l16])
                      : ((const float*)b)[nt * 16 + l16];
        acc[nt] = (f32x4){bj, bj, bj, bj};
    }
#pragma unroll
    for (int ks = 0; ks < 4; ++ks) {
        bf16x8 aHi = *(const bf16x8*)&hHi[(w * 16 + l16) * HSTR + ks * 32 + q * 8];
        bf16x8 aLo = *(const bf16x8*)&hLo[(w * 16 + l16) * HSTR + ks * 32 + q * 8];
#pragma unroll
        for (int nt = 0; nt < 8; ++nt) {
            bf16x8 bfr = *(const bf16x8*)(WT + (long)(nt * 16 + l16) * NDIM + ks * 32 + q * 8);
            acc[nt] = __builtin_amdgcn_mfma_f32_16x16x32_bf16(aHi, bfr, acc[nt], 0, 0, 0);
            acc[nt] = __builtin_amdgcn_mfma_f32_16x16x32_bf16(aLo, bfr, acc[nt], 0, 0, 0);
        }
    }

#pragma unroll
    for (int nt = 0; nt < 8; ++nt) {
        float s = 0.f, qs = 0.f;
#pragma unroll
        for (int r = 0; r < 4; ++r) {
            int row = row0 + w * 16 + q * 4 + r;
            if (row < M) {
                float v = acc[nt][r];
                hout[(long)row * NDIM + nt * 16 + l16] = v;
                s += v; qs += v * v;
            }
        }
        s += __shfl_xor(s, 16);  s += __shfl_xor(s, 32);
        qs += __shfl_xor(qs, 16); qs += __shfl_xor(qs, 32);
        if (nt == 2 * q || nt == 2 * q + 1) {
            redS[w][nt * 16 + l16] = s;
            redQ[w][nt * 16 + l16] = qs;
        }
    }
    __syncthreads();
    if (tid < NDIM) {
        atomicAdd(&stats[tid], redS[0][tid] + redS[1][tid] + redS[2][tid] + redS[3][tid]);
    } else {
        int c = tid - NDIM;
        atomicAdd(&stats[NDIM + c], redQ[0][c] + redQ[1][c] + redQ[2][c] + redQ[3][c]);
    }
}

// ---------------------------------------------------------------------------
// K6: out = relu(BN2(h2)) -> output dtype
// ---------------------------------------------------------------------------
__global__ __launch_bounds__(256) void bn2_out_kernel(
    const float* __restrict__ h2, const float* __restrict__ statsIn,
    const void* __restrict__ g, const void* __restrict__ beta,
    void* __restrict__ out, int M, const int* __restrict__ flag) {
    const bool bf = (*flag != 0);
    __shared__ float scaleL[NDIM];
    __shared__ float shiftL[NDIM];
    const int tid = threadIdx.x;
    if (tid < NDIM) {
        float s = statsIn[tid], qv = statsIn[NDIM + tid];
        float invM = 1.0f / (float)M;
        float mean = s * invM;
        float var = fmaxf(qv * invM - mean * mean, 0.0f) + 1e-5f;
        float gv = bf ? bf2f(((const u16*)g)[tid]) : ((const float*)g)[tid];
        float bv = bf ? bf2f(((const u16*)beta)[tid]) : ((const float*)beta)[tid];
        float sc = gv * rsqrtf(var);
        scaleL[tid] = sc;
        shiftL[tid] = bv - mean * sc;
    }
    __syncthreads();

    const int n4 = M * NDIM / 4;
    for (int i = blockIdx.x * 256 + tid; i < n4; i += gridDim.x * 256) {
        int c = (i & 31) * 4;
        float4 hv = *(const float4*)(h2 + (long)i * 4);
        float o0 = fmaxf(hv.x * scaleL[c + 0] + shiftL[c + 0], 0.0f);
        float o1 = fmaxf(hv.y * scaleL[c + 1] + shiftL[c + 1], 0.0f);
        float o2 = fmaxf(hv.z * scaleL[c + 2] + shiftL[c + 2], 0.0f);
        float o3 = fmaxf(hv.w * scaleL[c + 3] + shiftL[c + 3], 0.0f);
        if (bf) {
            ushort4 o;
            o.x = f2bf(o0); o.y = f2bf(o1); o.z = f2bf(o2); o.w = f2bf(o3);
            *(ushort4*)((u16*)out + (long)i * 4) = o;
        } else {
            *(float4*)((float*)out + (long)i * 4) = make_float4(o0, o1, o2, o3);
        }
    }
}

extern "C" void kernel_launch(void* const* d_in, const int* in_sizes, int n_in,
                              void* d_out, int out_size, void* d_ws, size_t ws_size,
                              hipStream_t stream) {
    const void* x         = d_in[0];
    const int*  ei        = (const int*)d_in[1];
    const void* edge_attr = d_in[2];
    const void* eps_p     = d_in[3];
    const void* We        = d_in[4];
    const void* be        = d_in[5];
    const void* W1        = d_in[6];
    const void* b1        = d_in[7];
    const void* g1        = d_in[8];
    const void* beta1     = d_in[9];
    const void* W2        = d_in[10];
    const void* b2        = d_in[11];
    const void* g2        = d_in[12];
    const void* beta2     = d_in[13];

    int N = in_sizes[0] / NDIM;                // 50000
    int E = in_sizes[1] / 2;                   // 800000
    const size_t nd = (size_t)N * NDIM;

    float* agg    = (float*)d_ws;              // [nd]; reused as h2
    float* h1     = agg + nd;                  // [nd]
    float* stats1 = h1 + nd;                   // [256]
    float* stats2 = stats1 + 256;              // [256]
    int*   flag   = (int*)(stats2 + 256);      // [4]
    int*   bsum   = flag + 4;                  // [256]
    u16*   WeT    = (u16*)(bsum + 256);        // [128*32]
    u16*   W1T    = WeT + NDIM * EDIM;         // [128*128]
    u16*   W2T    = W1T + NDIM * NDIM;         // [128*128]
    float* h2     = agg;                       // reuse

    // CSR scratch overlaid on h1 (dead before gemm1 writes h1)
    int* cnt     = (int*)h1;                   // [N]
    int* cur     = cnt + N;                    // [N]
    int* row_ptr = cur + N;                    // [N+1]
    int* eidx    = row_ptr + N + 1;            // [E]
    int* src_s   = eidx + E;                   // [E]

    // K1: cooperative CSR build (+zeroing, +dtype detect)
    {
        void* args[] = {
            (void*)&ei, (void*)&x, (void*)&cnt, (void*)&cur, (void*)&row_ptr,
            (void*)&eidx, (void*)&src_s, (void*)&stats1, (void*)&flag,
            (void*)&bsum, (void*)&N, (void*)&E
        };
        hipLaunchCooperativeKernel((const void*)csr_coop_kernel,
                                   dim3(256), dim3(256), args, 0, stream);
    }

    // K2: weight pre-transpose (bf16)
    prep_kernel<<<1, 256, 0, stream>>>(We, W1, W2, WeT, W1T, W2T, flag);

    // K3: aggregation (MFMA edge-embed)
    agg_kernel<<<2048, 256, 0, stream>>>(row_ptr, eidx, src_s, edge_attr, x,
                                         WeT, be, agg, N, flag);

    // K4..K6
    const int nblk = (N + 63) / 64;
    gemm1_kernel<<<nblk, 256, 0, stream>>>(x, agg, eps_p, W1T, b1, h1, stats1, N, flag);
    gemm2_kernel<<<nblk, 256, 0, stream>>>(h1, stats1, g1, beta1, W2T, b2, h2, stats2, N, flag);
    bn2_out_kernel<<<2048, 256, 0, stream>>>(h2, stats2, g2, beta2, d_out, N, flag);
}

// Round 8
// 543.199 us; speedup vs baseline: 2.7989x; 2.7989x over previous
//
#include <hip/hip_runtime.h>
#include <hip/hip_bf16.h>

typedef unsigned short u16;
typedef __attribute__((ext_vector_type(8))) short bf16x8;
typedef __attribute__((ext_vector_type(4))) float f32x4;

#define NDIM 128
#define EDIM 32
#define HSTR 136     // gemm h LDS stride (u16): 16B aligned, 2-way banks (free)

__device__ __forceinline__ float bf2f(u16 u) {
    union { unsigned int i; float f; } v; v.i = ((unsigned int)u) << 16; return v.f;
}
__device__ __forceinline__ u16 f2bf(float f) {
    __hip_bfloat16 h = __float2bfloat16(f);
    return *reinterpret_cast<u16*>(&h);
}

// ---------------------------------------------------------------------------
// K0: dtype detector (flag: 1 = bf16, 0 = fp32)
// ---------------------------------------------------------------------------
__global__ void detect_kernel(const void* __restrict__ x, int* __restrict__ flag) {
    __shared__ int cnt;
    if (threadIdx.x == 0) cnt = 0;
    __syncthreads();
    const u16* p = (const u16*)x;
    int crazy = 0;
    for (int i = threadIdx.x; i < 512; i += 64) {
        u16 v = p[2 * i];
        int e = (v >> 7) & 0xFF;
        if (e != 0 && (e < 100 || e > 150)) crazy++;
    }
    atomicAdd(&cnt, crazy);
    __syncthreads();
    if (threadIdx.x == 0) *flag = (cnt > 128) ? 0 : 1;
}

// ---------------------------------------------------------------------------
// CSR build: histogram -> scan -> scatter (plain dispatches; no coop)
// ---------------------------------------------------------------------------
__global__ __launch_bounds__(256) void hist_kernel(
    const int* __restrict__ ei, int* __restrict__ cnt, int E) {
    int e = blockIdx.x * 256 + threadIdx.x;
    if (e < E) atomicAdd(&cnt[ei[E + e]], 1);
}

__global__ __launch_bounds__(1024) void scan_kernel(
    const int* __restrict__ cnt, int* __restrict__ row_ptr, int N) {
    __shared__ int part[1024];
    const int t = threadIdx.x;
    const int chunk = (N + 1023) / 1024;
    const int lo = t * chunk;
    const int hi = min(lo + chunk, N);
    int s = 0;
    for (int i = lo; i < hi; ++i) s += cnt[i];
    part[t] = s;
    __syncthreads();
    for (int off = 1; off < 1024; off <<= 1) {
        int v = (t >= off) ? part[t - off] : 0;
        __syncthreads();
        part[t] += v;
        __syncthreads();
    }
    int run = (t == 0) ? 0 : part[t - 1];
    for (int i = lo; i < hi; ++i) { row_ptr[i] = run; run += cnt[i]; }
    if (t == 1023) row_ptr[N] = run;
}

__global__ __launch_bounds__(256) void scatter_kernel(
    const int* __restrict__ ei, const int* __restrict__ row_ptr,
    int* __restrict__ cur, int* __restrict__ eidx,
    int* __restrict__ src_sorted, int E) {
    int e = blockIdx.x * 256 + threadIdx.x;
    if (e < E) {
        int dst = ei[E + e];
        int slot = row_ptr[dst] + atomicAdd(&cur[dst], 1);
        eidx[slot] = e;
        src_sorted[slot] = ei[e];
    }
}

// ---------------------------------------------------------------------------
// K2: pre-transpose weights to bf16 in workspace (grid-stride, 64 blocks).
// WeT[d][k] (d<128,k<32), W1T[c][k], W2T[c][k] (c,k<128).
// ---------------------------------------------------------------------------
__global__ __launch_bounds__(256) void prep_kernel(
    const void* __restrict__ We, const void* __restrict__ W1,
    const void* __restrict__ W2, u16* __restrict__ WeT,
    u16* __restrict__ W1T, u16* __restrict__ W2T, const int* __restrict__ flag) {
    const bool bf = (*flag != 0);
    const int tid = blockIdx.x * 256 + threadIdx.x;
    const int nthr = gridDim.x * 256;
    for (int i = tid; i < NDIM * EDIM; i += nthr) {
        int k = i >> 7, d = i & 127;
        WeT[d * EDIM + k] = bf ? ((const u16*)We)[i] : f2bf(((const float*)We)[i]);
    }
    for (int i = tid; i < NDIM * NDIM; i += nthr) {
        int k = i >> 7, c = i & 127;
        W1T[c * NDIM + k] = bf ? ((const u16*)W1)[i] : f2bf(((const float*)W1)[i]);
        W2T[c * NDIM + k] = bf ? ((const u16*)W2)[i] : f2bf(((const float*)W2)[i]);
    }
}

// ---------------------------------------------------------------------------
// K3: CSR aggregation with MFMA edge-embed (both dtypes).
// One wave per node. Per 16-edge group:
//   A[m=edge(l16)][k=q*8+j] = attr row (bf16-cvt if fp32)
//   B[k][n=dim(l16)] = WeT, hoisted to VGPRs (8 frags, loop-invariant)
//   D = mfma(A, B, C=bias) -> relu + validity mask -> part[8]
// x stays fp32-exact; quad-parallel gather, LDS exchange per node.
// ---------------------------------------------------------------------------
__global__ __launch_bounds__(256) void agg_kernel(
    const int* __restrict__ row_ptr, const int* __restrict__ eidx,
    const int* __restrict__ src_sorted, const void* __restrict__ edge_attr,
    const void* __restrict__ x, const u16* __restrict__ WeT,
    const void* __restrict__ be, float* __restrict__ agg, int N,
    const int* __restrict__ flag) {
    const bool bf = (*flag != 0);
    __shared__ float xsumQ[4][4][NDIM];

    const int lane = threadIdx.x & 63;
    const int wid = threadIdx.x >> 6;
    const int q = lane >> 4, l16 = lane & 15;

    bf16x8 bfr[8];
#pragma unroll
    for (int nt = 0; nt < 8; ++nt)
        bfr[nt] = *(const bf16x8*)(WeT + (nt * 16 + l16) * EDIM + q * 8);
    f32x4 biasv[8];
#pragma unroll
    for (int nt = 0; nt < 8; ++nt) {
        float bv = bf ? bf2f(((const u16*)be)[nt * 16 + l16])
                      : ((const float*)be)[nt * 16 + l16];
        biasv[nt] = (f32x4){bv, bv, bv, bv};
    }

    const int gwave = blockIdx.x * 4 + wid;
    const int nwaves = gridDim.x * 4;

    for (int n = gwave; n < N; n += nwaves) {
        const int p0 = row_ptr[n], p1 = row_ptr[n + 1];
        float part[8];
#pragma unroll
        for (int nt = 0; nt < 8; ++nt) part[nt] = 0.0f;
        float xa[8];
#pragma unroll
        for (int j = 0; j < 8; ++j) xa[j] = 0.0f;

        for (int base = p0; base < p1; base += 16) {
            const int cnt = min(16, p1 - base);
            // x-gather: quad q handles edges base+q, +4, +8, +12
            if (bf) {
                for (int t = q; t < cnt; t += 4) {
                    int s = src_sorted[base + t];
                    const u16* xr = (const u16*)x + (long)s * NDIM + l16 * 8;
                    ushort4 a = *(const ushort4*)xr;
                    ushort4 b2 = *(const ushort4*)(xr + 4);
                    xa[0] += bf2f(a.x); xa[1] += bf2f(a.y);
                    xa[2] += bf2f(a.z); xa[3] += bf2f(a.w);
                    xa[4] += bf2f(b2.x); xa[5] += bf2f(b2.y);
                    xa[6] += bf2f(b2.z); xa[7] += bf2f(b2.w);
                }
            } else {
                for (int t = q; t < cnt; t += 4) {
                    int s = src_sorted[base + t];
                    const float* xr = (const float*)x + (long)s * NDIM + l16 * 8;
                    float4 a = *(const float4*)xr;
                    float4 b2 = *(const float4*)(xr + 4);
                    xa[0] += a.x; xa[1] += a.y; xa[2] += a.z; xa[3] += a.w;
                    xa[4] += b2.x; xa[5] += b2.y; xa[6] += b2.z; xa[7] += b2.w;
                }
            }
            // A-frag: attr row of edge base+l16
            int eid = eidx[min(base + l16, p1 - 1)];
            bf16x8 af;
            if (bf) {
                af = *(const bf16x8*)((const u16*)edge_attr + (long)eid * EDIM + q * 8);
            } else {
                const float* ar = (const float*)edge_attr + (long)eid * EDIM + q * 8;
                float4 a0 = *(const float4*)ar;
                float4 a1 = *(const float4*)(ar + 4);
                af[0] = (short)f2bf(a0.x); af[1] = (short)f2bf(a0.y);
                af[2] = (short)f2bf(a0.z); af[3] = (short)f2bf(a0.w);
                af[4] = (short)f2bf(a1.x); af[5] = (short)f2bf(a1.y);
                af[6] = (short)f2bf(a1.z); af[7] = (short)f2bf(a1.w);
            }
#pragma unroll
            for (int nt = 0; nt < 8; ++nt) {
                f32x4 c = __builtin_amdgcn_mfma_f32_16x16x32_bf16(af, bfr[nt], biasv[nt], 0, 0, 0);
#pragma unroll
                for (int r = 0; r < 4; ++r)
                    if (q * 4 + r < cnt) part[nt] += fmaxf(c[r], 0.0f);
            }
        }
        // cross-quad reduce of MFMA parts
#pragma unroll
        for (int nt = 0; nt < 8; ++nt) {
            part[nt] += __shfl_xor(part[nt], 16);
            part[nt] += __shfl_xor(part[nt], 32);
        }
        // exchange x partials through LDS (per-wave slice, wave-coherent)
        *(float4*)&xsumQ[wid][q][l16 * 8 + 0] = make_float4(xa[0], xa[1], xa[2], xa[3]);
        *(float4*)&xsumQ[wid][q][l16 * 8 + 4] = make_float4(xa[4], xa[5], xa[6], xa[7]);
#pragma unroll
        for (int j = 0; j < 2; ++j) {
            int nt = 2 * q + j;
            int d = nt * 16 + l16;
            float xs = xsumQ[wid][0][d] + xsumQ[wid][1][d] +
                       xsumQ[wid][2][d] + xsumQ[wid][3][d];
            agg[(long)n * NDIM + d] = part[nt] + xs;
        }
    }
}

// ---------------------------------------------------------------------------
// split h -> bf16 hi+lo in LDS (fp32-accurate through 2 MFMAs)
// ---------------------------------------------------------------------------
__device__ __forceinline__ void split_store(u16* hHi, u16* hLo, int r, int c, float4 h) {
    ushort4 hi, lo;
    hi.x = f2bf(h.x); lo.x = f2bf(h.x - bf2f(hi.x));
    hi.y = f2bf(h.y); lo.y = f2bf(h.y - bf2f(hi.y));
    hi.z = f2bf(h.z); lo.z = f2bf(h.z - bf2f(hi.z));
    hi.w = f2bf(h.w); lo.w = f2bf(h.w - bf2f(hi.w));
    *(ushort4*)&hHi[r * HSTR + c] = hi;
    *(ushort4*)&hLo[r * HSTR + c] = lo;
}

// ---------------------------------------------------------------------------
// K4: h0 = (1+eps)*x + agg ; h1 = h0 @ W1 + b1 ; col stats.
// B-frags straight from global W1T (32 KB, L1/L2-resident). 64 rows/block.
// ---------------------------------------------------------------------------
__global__ __launch_bounds__(256) void gemm1_kernel(
    const void* __restrict__ x, const float* __restrict__ agg,
    const void* __restrict__ eps_p, const u16* __restrict__ WT,
    const void* __restrict__ b, float* __restrict__ hout,
    float* __restrict__ stats, int M, const int* __restrict__ flag) {
    const bool bf = (*flag != 0);
    __shared__ u16 hHi[64 * HSTR];
    __shared__ u16 hLo[64 * HSTR];
    __shared__ float redS[4][NDIM];
    __shared__ float redQ[4][NDIM];

    const int tid = threadIdx.x;
    const int row0 = blockIdx.x * 64;
    const float onepeps = 1.0f + (bf ? bf2f(((const u16*)eps_p)[0])
                                     : ((const float*)eps_p)[0]);

#pragma unroll
    for (int i = 0; i < 8; ++i) {
        int idx = (tid + i * 256) * 4;
        int r = idx >> 7, c = idx & 127;
        int row = row0 + r;
        float4 h = make_float4(0.f, 0.f, 0.f, 0.f);
        if (row < M) {
            float4 ag = *(const float4*)(agg + (long)row * NDIM + c);
            float4 xv;
            if (bf) {
                ushort4 u = *(const ushort4*)((const u16*)x + (long)row * NDIM + c);
                xv = make_float4(bf2f(u.x), bf2f(u.y), bf2f(u.z), bf2f(u.w));
            } else {
                xv = *(const float4*)((const float*)x + (long)row * NDIM + c);
            }
            h = make_float4(onepeps * xv.x + ag.x, onepeps * xv.y + ag.y,
                            onepeps * xv.z + ag.z, onepeps * xv.w + ag.w);
        }
        split_store(hHi, hLo, r, c, h);
    }
    __syncthreads();

    const int lane = tid & 63, w = tid >> 6;
    const int q = lane >> 4, l16 = lane & 15;

    f32x4 acc[8];
#pragma unroll
    for (int nt = 0; nt < 8; ++nt) {
        float bj = bf ? bf2f(((const u16*)b)[nt * 16 + l16])
                      : ((const float*)b)[nt * 16 + l16];
        acc[nt] = (f32x4){bj, bj, bj, bj};
    }
#pragma unroll
    for (int ks = 0; ks < 4; ++ks) {
        bf16x8 aHi = *(const bf16x8*)&hHi[(w * 16 + l16) * HSTR + ks * 32 + q * 8];
        bf16x8 aLo = *(const bf16x8*)&hLo[(w * 16 + l16) * HSTR + ks * 32 + q * 8];
#pragma unroll
        for (int nt = 0; nt < 8; ++nt) {
            bf16x8 bfr = *(const bf16x8*)(WT + (long)(nt * 16 + l16) * NDIM + ks * 32 + q * 8);
            acc[nt] = __builtin_amdgcn_mfma_f32_16x16x32_bf16(aHi, bfr, acc[nt], 0, 0, 0);
            acc[nt] = __builtin_amdgcn_mfma_f32_16x16x32_bf16(aLo, bfr, acc[nt], 0, 0, 0);
        }
    }

#pragma unroll
    for (int nt = 0; nt < 8; ++nt) {
        float s = 0.f, qs = 0.f;
#pragma unroll
        for (int r = 0; r < 4; ++r) {
            int row = row0 + w * 16 + q * 4 + r;
            if (row < M) {
                float v = acc[nt][r];
                hout[(long)row * NDIM + nt * 16 + l16] = v;
                s += v; qs += v * v;
            }
        }
        s += __shfl_xor(s, 16);  s += __shfl_xor(s, 32);
        qs += __shfl_xor(qs, 16); qs += __shfl_xor(qs, 32);
        if (nt == 2 * q || nt == 2 * q + 1) {
            redS[w][nt * 16 + l16] = s;
            redQ[w][nt * 16 + l16] = qs;
        }
    }
    __syncthreads();
    if (tid < NDIM) {
        atomicAdd(&stats[tid], redS[0][tid] + redS[1][tid] + redS[2][tid] + redS[3][tid]);
    } else {
        int c = tid - NDIM;
        atomicAdd(&stats[NDIM + c], redQ[0][c] + redQ[1][c] + redQ[2][c] + redQ[3][c]);
    }
}

// ---------------------------------------------------------------------------
// K5: a = relu(BN1(h1)) ; h2 = a @ W2 + b2 ; col stats.
// ---------------------------------------------------------------------------
__global__ __launch_bounds__(256) void gemm2_kernel(
    const float* __restrict__ h1, const float* __restrict__ statsIn,
    const void* __restrict__ g, const void* __restrict__ beta,
    const u16* __restrict__ WT, const void* __restrict__ b,
    float* __restrict__ hout, float* __restrict__ stats, int M,
    const int* __restrict__ flag) {
    const bool bf = (*flag != 0);
    __shared__ u16 hHi[64 * HSTR];
    __shared__ u16 hLo[64 * HSTR];
    __shared__ float redS[4][NDIM];
    __shared__ float redQ[4][NDIM];
    __shared__ float scaleL[NDIM];
    __shared__ float shiftL[NDIM];

    const int tid = threadIdx.x;
    const int row0 = blockIdx.x * 64;

    if (tid < NDIM) {
        float s = statsIn[tid], qv = statsIn[NDIM + tid];
        float invM = 1.0f / (float)M;
        float mean = s * invM;
        float var = fmaxf(qv * invM - mean * mean, 0.0f) + 1e-5f;
        float gv = bf ? bf2f(((const u16*)g)[tid]) : ((const float*)g)[tid];
        float bv = bf ? bf2f(((const u16*)beta)[tid]) : ((const float*)beta)[tid];
        float sc = gv * rsqrtf(var);
        scaleL[tid] = sc;
        shiftL[tid] = bv - mean * sc;
    }
    __syncthreads();

#pragma unroll
    for (int i = 0; i < 8; ++i) {
        int idx = (tid + i * 256) * 4;
        int r = idx >> 7, c = idx & 127;
        int row = row0 + r;
        float4 h = make_float4(0.f, 0.f, 0.f, 0.f);
        if (row < M) {
            float4 hv = *(const float4*)(h1 + (long)row * NDIM + c);
            h.x = fmaxf(hv.x * scaleL[c + 0] + shiftL[c + 0], 0.0f);
            h.y = fmaxf(hv.y * scaleL[c + 1] + shiftL[c + 1], 0.0f);
            h.z = fmaxf(hv.z * scaleL[c + 2] + shiftL[c + 2], 0.0f);
            h.w = fmaxf(hv.w * scaleL[c + 3] + shiftL[c + 3], 0.0f);
        }
        split_store(hHi, hLo, r, c, h);
    }
    __syncthreads();

    const int lane = tid & 63, w = tid >> 6;
    const int q = lane >> 4, l16 = lane & 15;

    f32x4 acc[8];
#pragma unroll
    for (int nt = 0; nt < 8; ++nt) {
        float bj = bf ? bf2f(((const u16*)b)[nt * 16 + l16])
                      : ((const float*)b)[nt * 16 + l16];
        acc[nt] = (f32x4){bj, bj, bj, bj};
    }
#pragma unroll
    for (int ks = 0; ks < 4; ++ks) {
        bf16x8 aHi = *(const bf16x8*)&hHi[(w * 16 + l16) * HSTR + ks * 32 + q * 8];
        bf16x8 aLo = *(const bf16x8*)&hLo[(w * 16 + l16) * HSTR + ks * 32 + q * 8];
#pragma unroll
        for (int nt = 0; nt < 8; ++nt) {
            bf16x8 bfr = *(const bf16x8*)(WT + (long)(nt * 16 + l16) * NDIM + ks * 32 + q * 8);
            acc[nt] = __builtin_amdgcn_mfma_f32_16x16x32_bf16(aHi, bfr, acc[nt], 0, 0, 0);
            acc[nt] = __builtin_amdgcn_mfma_f32_16x16x32_bf16(aLo, bfr, acc[nt], 0, 0, 0);
        }
    }

#pragma unroll
    for (int nt = 0; nt < 8; ++nt) {
        float s = 0.f, qs = 0.f;
#pragma unroll
        for (int r = 0; r < 4; ++r) {
            int row = row0 + w * 16 + q * 4 + r;
            if (row < M) {
                float v = acc[nt][r];
                hout[(long)row * NDIM + nt * 16 + l16] = v;
                s += v; qs += v * v;
            }
        }
        s += __shfl_xor(s, 16);  s += __shfl_xor(s, 32);
        qs += __shfl_xor(qs, 16); qs += __shfl_xor(qs, 32);
        if (nt == 2 * q || nt == 2 * q + 1) {
            redS[w][nt * 16 + l16] = s;
            redQ[w][nt * 16 + l16] = qs;
        }
    }
    __syncthreads();
    if (tid < NDIM) {
        atomicAdd(&stats[tid], redS[0][tid] + redS[1][tid] + redS[2][tid] + redS[3][tid]);
    } else {
        int c = tid - NDIM;
        atomicAdd(&stats[NDIM + c], redQ[0][c] + redQ[1][c] + redQ[2][c] + redQ[3][c]);
    }
}

// ---------------------------------------------------------------------------
// K6: out = relu(BN2(h2)) -> output dtype
// ---------------------------------------------------------------------------
__global__ __launch_bounds__(256) void bn2_out_kernel(
    const float* __restrict__ h2, const float* __restrict__ statsIn,
    const void* __restrict__ g, const void* __restrict__ beta,
    void* __restrict__ out, int M, const int* __restrict__ flag) {
    const bool bf = (*flag != 0);
    __shared__ float scaleL[NDIM];
    __shared__ float shiftL[NDIM];
    const int tid = threadIdx.x;
    if (tid < NDIM) {
        float s = statsIn[tid], qv = statsIn[NDIM + tid];
        float invM = 1.0f / (float)M;
        float mean = s * invM;
        float var = fmaxf(qv * invM - mean * mean, 0.0f) + 1e-5f;
        float gv = bf ? bf2f(((const u16*)g)[tid]) : ((const float*)g)[tid];
        float bv = bf ? bf2f(((const u16*)beta)[tid]) : ((const float*)beta)[tid];
        float sc = gv * rsqrtf(var);
        scaleL[tid] = sc;
        shiftL[tid] = bv - mean * sc;
    }
    __syncthreads();

    const int n4 = M * NDIM / 4;
    for (int i = blockIdx.x * 256 + tid; i < n4; i += gridDim.x * 256) {
        int c = (i & 31) * 4;
        float4 hv = *(const float4*)(h2 + (long)i * 4);
        float o0 = fmaxf(hv.x * scaleL[c + 0] + shiftL[c + 0], 0.0f);
        float o1 = fmaxf(hv.y * scaleL[c + 1] + shiftL[c + 1], 0.0f);
        float o2 = fmaxf(hv.z * scaleL[c + 2] + shiftL[c + 2], 0.0f);
        float o3 = fmaxf(hv.w * scaleL[c + 3] + shiftL[c + 3], 0.0f);
        if (bf) {
            ushort4 o;
            o.x = f2bf(o0); o.y = f2bf(o1); o.z = f2bf(o2); o.w = f2bf(o3);
            *(ushort4*)((u16*)out + (long)i * 4) = o;
        } else {
            *(float4*)((float*)out + (long)i * 4) = make_float4(o0, o1, o2, o3);
        }
    }
}

extern "C" void kernel_launch(void* const* d_in, const int* in_sizes, int n_in,
                              void* d_out, int out_size, void* d_ws, size_t ws_size,
                              hipStream_t stream) {
    const void* x         = d_in[0];
    const int*  ei        = (const int*)d_in[1];
    const void* edge_attr = d_in[2];
    const void* eps_p     = d_in[3];
    const void* We        = d_in[4];
    const void* be        = d_in[5];
    const void* W1        = d_in[6];
    const void* b1        = d_in[7];
    const void* g1        = d_in[8];
    const void* beta1     = d_in[9];
    const void* W2        = d_in[10];
    const void* b2        = d_in[11];
    const void* g2        = d_in[12];
    const void* beta2     = d_in[13];

    int N = in_sizes[0] / NDIM;                // 50000
    int E = in_sizes[1] / 2;                   // 800000
    const size_t nd = (size_t)N * NDIM;

    float* agg    = (float*)d_ws;              // [nd]; reused as h2
    float* h1     = agg + nd;                  // [nd]
    float* stats1 = h1 + nd;                   // [256]
    float* stats2 = stats1 + 256;              // [256]
    int*   flag   = (int*)(stats2 + 256);      // [4]
    u16*   WeT    = (u16*)(flag + 4);          // [128*32]
    u16*   W1T    = WeT + NDIM * EDIM;         // [128*128]
    u16*   W2T    = W1T + NDIM * NDIM;         // [128*128]
    float* h2     = agg;                       // reuse

    // CSR scratch overlaid on h1 (dead before gemm1 writes h1)
    int* cnt     = (int*)h1;                   // [N]
    int* cur     = cnt + N;                    // [N]
    int* row_ptr = cur + N;                    // [N+1]
    int* eidx    = row_ptr + N + 1;            // [E]
    int* src_s   = eidx + E;                   // [E]

    detect_kernel<<<1, 64, 0, stream>>>(x, flag);
    hipMemsetAsync(stats1, 0, 512 * sizeof(float), stream);
    hipMemsetAsync(cnt, 0, 2 * (size_t)N * sizeof(int), stream);

    const int eblk = (E + 255) / 256;
    hist_kernel<<<eblk, 256, 0, stream>>>(ei, cnt, E);
    scan_kernel<<<1, 1024, 0, stream>>>(cnt, row_ptr, N);
    scatter_kernel<<<eblk, 256, 0, stream>>>(ei, row_ptr, cur, eidx, src_s, E);

    prep_kernel<<<64, 256, 0, stream>>>(We, W1, W2, WeT, W1T, W2T, flag);

    agg_kernel<<<2048, 256, 0, stream>>>(row_ptr, eidx, src_s, edge_attr, x,
                                         WeT, be, agg, N, flag);

    const int nblk = (N + 63) / 64;
    gemm1_kernel<<<nblk, 256, 0, stream>>>(x, agg, eps_p, W1T, b1, h1, stats1, N, flag);
    gemm2_kernel<<<nblk, 256, 0, stream>>>(h1, stats1, g1, beta1, W2T, b2, h2, stats2, N, flag);
    bn2_out_kernel<<<2048, 256, 0, stream>>>(h2, stats2, g2, beta2, d_out, N, flag);
}